// Round 10
// baseline (387.487 us; speedup 1.0000x reference)
//
#include <hip/hip_runtime.h>
#include <hip/hip_bf16.h>

// ZeroPadder: out[b,t,0:1024] = x[b,t,:], out[b,t,1024:2048] = 0
// x: [16, 2048, 1024] f32 -> out: [16, 2048, 2048] f32 (32768 rows).
//
// DISCRIMINATOR ROUND: split into two uniform-stream kernels at minimum
// total traffic (128 MiB read + 256 MiB write, nothing written twice):
//   zp_zero: pure-write stream of the zero halves (the mix that the harness
//            fills run at 6.5 TB/s)
//   zp_copy: 1:1 read:write copy of x into the copy halves (the mix m13's
//            copy benchmark runs at 6.29 TB/s)
// If the previous single kernel (~115 us est.) was limited by its fused
// 1-read:2-write interleave, this drops ~50 us. If it was already ~65 us
// (model B), this costs a few us and we declare roofline next round.
//
// Chunk math (float4 units): copy chunk c -> row=c>>8, col=c&255;
// out idx = row*512+col = c + (c & ~255); zero half adds +256.

typedef float f32x4 __attribute__((ext_vector_type(4)));

#define THREADS 256
#define BLOCKS  2048
#define T_TOTAL (THREADS * BLOCKS)   // 524288 threads
#define ITERS   16                   // 16 * 524288 = 8,388,608 chunks per half

__global__ __launch_bounds__(THREADS) void zp_zero(f32x4* __restrict__ out) {
    const int t = blockIdx.x * THREADS + threadIdx.x;
    const f32x4 z = {0.f, 0.f, 0.f, 0.f};
    #pragma unroll
    for (int i = 0; i < ITERS; ++i) {
        int c = t + i * T_TOTAL;
        out[c + (c & ~255) + 256] = z;
    }
}

__global__ __launch_bounds__(THREADS) void zp_copy(
    const f32x4* __restrict__ x, f32x4* __restrict__ out) {
    const int t = blockIdx.x * THREADS + threadIdx.x;
    #pragma unroll
    for (int i = 0; i < ITERS; ++i) {
        int c = t + i * T_TOTAL;
        f32x4 v = x[c];
        out[c + (c & ~255)] = v;
    }
}

extern "C" void kernel_launch(void* const* d_in, const int* in_sizes, int n_in,
                              void* d_out, int out_size, void* d_ws, size_t ws_size,
                              hipStream_t stream) {
    const f32x4* x = (const f32x4*)d_in[0];
    // d_in[1] (identity+zero weight) unused: the matmul is a pure zero-pad.
    f32x4* out = (f32x4*)d_out;
    zp_zero<<<BLOCKS, THREADS, 0, stream>>>(out);
    zp_copy<<<BLOCKS, THREADS, 0, stream>>>(x, out);
}